// Round 17
// baseline (44.719 us; speedup 1.0000x reference)
//
#include <hip/hip_runtime.h>
#include <hip/hip_bf16.h>

// Attention: B=512, T=128, C=512, H=64. out[b,t,h] f32.
// R17: persistent cross-element pipeline. Grid 256 (1 block/CU), each block
// does 2 batch elements as ONE continuous 32-chunk stream; element-0's
// attention runs while element-1's W/x prefetches (issued at chunks 13-15)
// are in flight. 4 W LDS buffers (staged +3 ahead), 4 x register slots
// (issued +4 ahead), exact per-chunk vmcnt ladder (out-stores counted as
// ballast at c=16..18). LDS 144K: W[4][16K] | qs | ks | vst | ps.

#define TT 128
#define CC 512
#define HH 64

typedef __attribute__((ext_vector_type(8))) short bf16x8;
typedef __attribute__((ext_vector_type(4))) ushort u16x4;
typedef __attribute__((ext_vector_type(4))) float f32x4;

__device__ __forceinline__ ushort f2bf(float f) {
    union { float f; unsigned u; } v; v.f = f;
    unsigned r = v.u + 0x7fffu + ((v.u >> 16) & 1u);  // RNE
    return (ushort)(r >> 16);
}

__device__ __forceinline__ void gload_lds16(const void* g, void* l) {
    __builtin_amdgcn_global_load_lds(
        (const __attribute__((address_space(1))) unsigned int*)g,
        (__attribute__((address_space(3))) unsigned int*)l, 16, 0, 0);
}

__device__ __forceinline__ void waitv(int n) {
    switch (n) {
    case 0:  asm volatile("s_waitcnt vmcnt(0)"  ::: "memory"); break;
    case 2:  asm volatile("s_waitcnt vmcnt(2)"  ::: "memory"); break;
    case 4:  asm volatile("s_waitcnt vmcnt(4)"  ::: "memory"); break;
    case 6:  asm volatile("s_waitcnt vmcnt(6)"  ::: "memory"); break;
    case 8:  asm volatile("s_waitcnt vmcnt(8)"  ::: "memory"); break;
    case 10: asm volatile("s_waitcnt vmcnt(10)" ::: "memory"); break;
    case 12: asm volatile("s_waitcnt vmcnt(12)" ::: "memory"); break;
    case 14: asm volatile("s_waitcnt vmcnt(14)" ::: "memory"); break;
    case 16: asm volatile("s_waitcnt vmcnt(16)" ::: "memory"); break;
    case 18: asm volatile("s_waitcnt vmcnt(18)" ::: "memory"); break;
    case 20: asm volatile("s_waitcnt vmcnt(20)" ::: "memory"); break;
    default: asm volatile("s_waitcnt vmcnt(30)" ::: "memory"); break;
    }
    __builtin_amdgcn_sched_barrier(0);
}

// ---- wpack: chunk ks stride 8192 ushorts (16KB, last 4KB pad unused) ----
__global__ void wpack_kernel(const float* __restrict__ wq,
                             const float* __restrict__ wk,
                             const float* __restrict__ wv,
                             ushort* __restrict__ wpk) {
    int p = blockIdx.x * 256 + threadIdx.x;   // 0..98303
    int j  = p & 7;
    int l  = (p >> 3) & 63;
    int nt = (p >> 9) % 12;
    int kt = p / (12 * 512);
    int w  = nt >> 2;
    const float* src = (w == 0) ? wq : ((w == 1) ? wk : wv);
    int h = (nt & 3) * 16 + (l & 15);
    int c = kt * 32 + ((l >> 4) << 3) + j;
    wpk[kt * 8192 + ((nt * 64 + l) * 8) + j] = f2bf(src[h * 512 + c]);
}

// vmcnt ladders, indexed by global chunk c (0..31)
__constant__ const int kWX[32] = {8,10,12,14,14,14,14,14,14,14,14,14,14,14,14,14,
                                  30,30,30,30,14,14,14,14,14,14,14,14,14,10,6,2};
__constant__ const int kWW[32] = {16,18,20,14,14,14,14,14,14,14,14,14,14,14,14,14,
                                  30,30,30,14,14,14,14,14,14,14,14,14,12,8,4,0};

// ---- persistent fused: 256 blocks, 8 waves, 2 batch elements each ----
__launch_bounds__(512, 2)
__global__ void attn_fused_kernel(const float* __restrict__ x,
                                  const ushort* __restrict__ wpk,
                                  float* __restrict__ out) {
    // 144 KB LDS -> 1 block/CU.
    __shared__ __align__(16) char smem[147456];
    ushort* qs  = (ushort*)(smem + 65536);     // [128][64] swizzled col^((t&7)<<3)
    ushort* ks  = (ushort*)(smem + 81920);     // [128][64] swizzled
    ushort* vst = (ushort*)(smem + 98304);     // [64][128] V^T, swizzled t^((h&7)<<3)
    ushort* ps  = (ushort*)(smem + 114688);    // [128][128] P, private region

    const int tid  = threadIdx.x;
    const int wave = tid >> 6;
    const int lane = tid & 63;
    const int lq   = lane >> 4;
    const int lr   = lane & 15;
    const int b0   = blockIdx.x * 2;
    const int b1   = b0 + 1;

    const f32x4 fzero = {0.f, 0.f, 0.f, 0.f};
    const int r = wave * 16 + lr;                          // block-local row
    const float* xr0 = x + ((size_t)b0 * TT + r) * CC + lq * 8;
    const float* xr1 = x + ((size_t)b1 * TT + r) * CC + lq * 8;

    auto stageW = [&](int c, int buf) {                    // W chunk c%16 -> buf
        const char* wsrc = (const char*)wpk + (c & 15) * 16384;
        char* wdst = smem + buf * 16384;
        #pragma unroll
        for (int p = 0; p < 2; ++p) {
            int off = wave * 2048 + p * 1024;
            gload_lds16(wsrc + off + lane * 16, wdst + off);
        }
    };

    #define LOADX(c, dlo, dhi)                                                 \
        {                                                                      \
            const float* p0 = ((c) < 16 ? xr0 : xr1) + ((c) & 15) * 32;        \
            asm volatile("global_load_dwordx4 %0, %1, off"                     \
                         : "=&v"(dlo) : "v"(p0) : "memory");                   \
            asm volatile("global_load_dwordx4 %0, %1, off offset:16"           \
                         : "=&v"(dhi) : "v"(p0) : "memory");                   \
        }

    f32x4 x0a, x0b, x1a, x1b, x2a, x2b, x3a, x3b;          // 4 rotating slots
    f32x4 acc[12];

    // attention tail for element b (reads qs/ks/vst/ps; out stores counted
    // as vmcnt ballast by the resume ladder)
    auto do_attn = [&](int b, float* ob) {
        const int row0 = wave * 16;
        f32x4 s[8];
        #pragma unroll
        for (int j = 0; j < 8; ++j) s[j] = fzero;
        #pragma unroll
        for (int kt2 = 0; kt2 < 2; ++kt2) {
            int h0 = kt2 * 32 + lq * 8;
            int t  = row0 + lr;
            bf16x8 a = *(const bf16x8*)&qs[t * 64 + (h0 ^ ((t & 7) << 3))];
            bf16x8 kf[8];
            #pragma unroll
            for (int nt = 0; nt < 8; ++nt) {
                int sc = nt * 16 + lr;
                kf[nt] = *(const bf16x8*)&ks[sc * 64 + (h0 ^ ((sc & 7) << 3))];
            }
            #pragma unroll
            for (int nt = 0; nt < 8; ++nt)
                s[nt] = __builtin_amdgcn_mfma_f32_16x16x32_bf16(a, kf[nt], s[nt], 0, 0, 0);
        }
        float rinv[4];
        #pragma unroll
        for (int j = 0; j < 4; ++j) {
            int t = row0 + lq * 4 + j;
            float m = -1e30f;
            #pragma unroll
            for (int nt = 0; nt < 8; ++nt) {
                int sc = nt * 16 + lr;
                float v = s[nt][j] * 0.125f;
                v = (sc <= t) ? v : -1e30f;
                s[nt][j] = v;
                m = fmaxf(m, v);
            }
            m = fmaxf(m, __shfl_xor(m, 1));
            m = fmaxf(m, __shfl_xor(m, 2));
            m = fmaxf(m, __shfl_xor(m, 4));
            m = fmaxf(m, __shfl_xor(m, 8));
            float sum = 0.f;
            #pragma unroll
            for (int nt = 0; nt < 8; ++nt) {
                float p = __expf(s[nt][j] - m);
                s[nt][j] = p;
                sum += p;
            }
            sum += __shfl_xor(sum, 1);
            sum += __shfl_xor(sum, 2);
            sum += __shfl_xor(sum, 4);
            sum += __shfl_xor(sum, 8);
            rinv[j] = 1.0f / sum;
        }
        // P -> private ps region (wave-private rows; no block barrier)
        #pragma unroll
        for (int j = 0; j < 4; ++j) {
            int t = row0 + lq * 4 + j;
            #pragma unroll
            for (int nt = 0; nt < 8; ++nt) {
                int sc = nt * 16 + lr;
                ps[t * 128 + (sc ^ ((t & 7) << 3))] = f2bf(s[nt][j]);
            }
        }
        f32x4 o[4];
        #pragma unroll
        for (int j = 0; j < 4; ++j) o[j] = fzero;
        #pragma unroll
        for (int ksv = 0; ksv < 4; ++ksv) {
            int s0 = ksv * 32 + lq * 8;
            int t  = row0 + lr;
            bf16x8 a = *(const bf16x8*)&ps[t * 128 + (s0 ^ ((t & 7) << 3))];
            bf16x8 vf[4];
            #pragma unroll
            for (int nt = 0; nt < 4; ++nt) {
                int h = nt * 16 + lr;
                vf[nt] = *(const bf16x8*)&vst[h * 128 + (s0 ^ ((h & 7) << 3))];
            }
            #pragma unroll
            for (int nt = 0; nt < 4; ++nt)
                o[nt] = __builtin_amdgcn_mfma_f32_16x16x32_bf16(a, vf[nt], o[nt], 0, 0, 0);
        }
        #pragma unroll
        for (int nt = 0; nt < 4; ++nt)
            #pragma unroll
            for (int j = 0; j < 4; ++j) {
                int t = row0 + lq * 4 + j;
                int h = nt * 16 + lr;
                ob[t * HH + h] = o[nt][j] * rinv[j];
            }
    };

    // ---- prologue: W0,W1,W2 staged; x0..x3 issued ----
    stageW(0, 0); stageW(1, 1); stageW(2, 2);
    LOADX(0, x0a, x0b); LOADX(1, x1a, x1b);
    LOADX(2, x2a, x2b); LOADX(3, x3a, x3b);

    #pragma unroll
    for (int e = 0; e < 2; ++e) {
        #pragma unroll
        for (int j = 0; j < 12; ++j) acc[j] = fzero;

        #pragma unroll
        for (int k = 0; k < 16; ++k) {
            const int c = e * 16 + k;
            const int slot = c & 3;

            // barrier 1: all waves done consuming chunk c-1
            __builtin_amdgcn_s_barrier();

            if (c + 3 < 32) stageW(c + 3, (c + 3) & 3);

            waitv(kWX[c]);                       // x(c) arrived
            f32x4 alo, ahi;
            if (slot == 0)      { alo = x0a; ahi = x0b; }
            else if (slot == 1) { alo = x1a; ahi = x1b; }
            else if (slot == 2) { alo = x2a; ahi = x2b; }
            else                { alo = x3a; ahi = x3b; }
            bf16x8 a;
            a[0] = (short)f2bf(alo[0]); a[1] = (short)f2bf(alo[1]);
            a[2] = (short)f2bf(alo[2]); a[3] = (short)f2bf(alo[3]);
            a[4] = (short)f2bf(ahi[0]); a[5] = (short)f2bf(ahi[1]);
            a[6] = (short)f2bf(ahi[2]); a[7] = (short)f2bf(ahi[3]);

            if (c + 4 < 32) {                    // refill the slot just consumed
                if (slot == 0)      LOADX(c + 4, x0a, x0b)
                else if (slot == 1) LOADX(c + 4, x1a, x1b)
                else if (slot == 2) LOADX(c + 4, x2a, x2b)
                else                LOADX(c + 4, x3a, x3b)
            }

            waitv(kWW[c]);                       // W(c) landed in LDS
            __builtin_amdgcn_s_barrier();        // barrier 2: W(c) visible
            __builtin_amdgcn_sched_barrier(0);

            const ushort* wf = (const ushort*)(smem + (c & 3) * 16384);
            bf16x8 w[12];
            #pragma unroll
            for (int nt = 0; nt < 12; ++nt)
                w[nt] = *(const bf16x8*)(wf + (nt * 64 + lane) * 8);
            #pragma unroll
            for (int nt = 0; nt < 12; ++nt)
                acc[nt] = __builtin_amdgcn_mfma_f32_16x16x32_bf16(a, w[nt], acc[nt], 0, 0, 0);
        }

        // ---- QKV epilogue -> attention LDS ----
        {
            const int t0 = wave * 16 + lq * 4;
            #pragma unroll
            for (int nt = 0; nt < 8; ++nt)
                #pragma unroll
                for (int j = 0; j < 4; ++j) {
                    int t = t0 + j;
                    int h = (nt & 3) * 16 + lr;
                    ushort v = f2bf(acc[nt][j]);
                    if (nt < 4) qs[t * 64 + (h ^ ((t & 7) << 3))] = v;
                    else        ks[t * 64 + (h ^ ((t & 7) << 3))] = v;
                }
            #pragma unroll
            for (int nt = 8; nt < 12; ++nt) {
                int h = (nt & 3) * 16 + lr;
                int base = t0 ^ ((h & 7) << 3);
                u16x4 v4;
                v4[0] = f2bf(acc[nt][0]); v4[1] = f2bf(acc[nt][1]);
                v4[2] = f2bf(acc[nt][2]); v4[3] = f2bf(acc[nt][3]);
                *(u16x4*)&vst[h * 128 + base] = v4;
            }
        }
        __syncthreads();                         // QKV visible to all waves

        do_attn(e ? b1 : b0,
                out + (size_t)(e ? b1 : b0) * (TT * HH));
        // element 1's prefetches (chunks 16-19) have been streaming the
        // whole time; resume ladder (kWX/kWW[16..]) counts the 16 out
        // stores as ballast.
    }
}

extern "C" void kernel_launch(void* const* d_in, const int* in_sizes, int n_in,
                              void* d_out, int out_size, void* d_ws, size_t ws_size,
                              hipStream_t stream) {
    const float* x  = (const float*)d_in[0];
    const float* wq = (const float*)d_in[1];
    const float* wk = (const float*)d_in[2];
    const float* wv = (const float*)d_in[3];
    float* o = (float*)d_out;
    ushort* wpk = (ushort*)d_ws;    // 16 chunks x 16KB = 256 KB packed W

    (void)in_sizes; (void)n_in; (void)out_size; (void)ws_size;

    wpack_kernel<<<384, 256, 0, stream>>>(wq, wk, wv, wpk);
    attn_fused_kernel<<<256, 512, 0, stream>>>(x, wpk, o);
}